// Round 11
// baseline (629.486 us; speedup 1.0000x reference)
//
#include <hip/hip_runtime.h>
#include <hip/hip_cooperative_groups.h>
#include <math.h>

namespace cg = cooperative_groups;

#define NN 8192
// out = elu(0.5*h_s + (sum_j w_ij h_n_j)/Z_i), w_ij = adj_ij * exp(relu(s_i+n_j))
// Factorization: exp(relu(s+n)) = max(exp(s)*exp(n), 1) (exp monotone) ->
// precompute es=exp(s), en=exp(n); NO transcendental in the O(N^2) loop.

typedef short short8 __attribute__((ext_vector_type(8)));   // 8 bf16 (4 VGPRs)
typedef float f32x4 __attribute__((ext_vector_type(4)));

__device__ __forceinline__ float eluf(float x) {
  return x > 0.f ? x : (__expf(x) - 1.f);
}
__device__ __forceinline__ unsigned short f2bf(float f) {
  union { float f; unsigned u; } v; v.f = f;
  unsigned r = v.u + 0x7fffu + ((v.u >> 16) & 1u);  // RNE
  return (unsigned short)(r >> 16);
}
__device__ __forceinline__ unsigned pack4(int4 v, int sh) {
  return ((unsigned)(v.x & 1) << sh) | ((unsigned)(v.y & 1) << (sh + 1)) |
         ((unsigned)(v.z & 1) << (sh + 2)) | ((unsigned)(v.w & 1) << (sh + 3));
}

// ================= Fused cooperative kernel =================
// 256 blocks x 1024 threads (1 block/CU, all co-resident -> grid.sync valid).
// Phase 1 (parity-ordered for overlap: even blocks pack->proj, odd proj->pack):
//   PACK: this block's 32 adj rows -> bits_lds (32 KB) DIRECTLY (no global P).
//   PROJ: 4x 256-thread units, each the R7-verified proj body for 8 rows
//         (scratch = low 32 KB of smem) -> Hs, HnT, es=exp(s), en=exp(n).
// grid.sync() (cooperative; includes the cross-XCD fencing).
// Phase 2: stage en into LDS (overwrites proj scratch), then the R10-verified
//   loop (compile-time tt strides, single breg generation after MFMA block,
//   branch-free overrun prefetch) + R10-verified epilogue tree.
__global__ __launch_bounds__(1024, 4) void k_fused(const float* __restrict__ X,
                                                   const int* __restrict__ A,
                                                   const float* __restrict__ Ws,
                                                   const float* __restrict__ Wn,
                                                   const float* __restrict__ as_,
                                                   const float* __restrict__ an_,
                                                   float* __restrict__ HsOut,
                                                   unsigned short* __restrict__ HnT,
                                                   float* __restrict__ es_g,
                                                   float* __restrict__ en_g) {
  __shared__ __align__(16) char smem[65536];           // 64 KB
  unsigned* bits_lds = (unsigned*)(smem + 32768);      // 8192 u32 = 32 KB (persistent)
  __shared__ float zsh[8][32];
  __shared__ float zf[32];

  const int t = threadIdx.x;
  const int bid = blockIdx.x;
  const int row0 = bid * 32;

  // ---------------- phase 1 ----------------
  auto do_pack = [&]() {
#pragma unroll 1
    for (int k = 0; k < 8; ++k) {
      int g = t + k * 1024;           // 0..8191
      int rr = g >> 8;                // row-in-block 0..31
      int c8 = g & 255;               // word-in-row (= j/32)
      const int4* src = (const int4*)(A + (size_t)(row0 + rr) * NN + c8 * 32);
      int4 v0 = src[0], v1 = src[1], v2 = src[2], v3 = src[3];
      int4 v4 = src[4], v5 = src[5], v6 = src[6], v7 = src[7];
      unsigned w = pack4(v0, 0)  | pack4(v1, 4)  | pack4(v2, 8)  | pack4(v3, 12) |
                   pack4(v4, 16) | pack4(v5, 20) | pack4(v6, 24) | pack4(v7, 28);
      // LDS layout [jp][tt][32 rows] (verified R10 composition)
      bits_lds[(c8 >> 5) * 1024 + (c8 & 31) * 32 + rr] = w;
    }
  };

  auto do_proj = [&]() {
    const int tl = t & 255;           // thread-in-unit
    const int u = t >> 8;             // unit 0..3
    const int i0 = row0 + u * 8;      // 8 rows per unit
    float4* S4 = (float4*)smem + u * 512;   // 8 KB scratch per unit
    const float4* Xg = (const float4*)X + (size_t)i0 * 64;
    S4[tl] = Xg[tl];
    S4[tl + 256] = Xg[tl + 256];
    __syncthreads();
    const int c = tl & 127;
    const int rh = tl >> 7;  // 0..1, 4 rows each
    float accs[4], accn[4];
#pragma unroll
    for (int r = 0; r < 4; ++r) { accs[r] = 0.f; accn[r] = 0.f; }
    for (int k = 0; k < 256; k += 4) {
      float ws0 = Ws[(k + 0) * 128 + c], ws1 = Ws[(k + 1) * 128 + c];
      float ws2 = Ws[(k + 2) * 128 + c], ws3 = Ws[(k + 3) * 128 + c];
      float wn0 = Wn[(k + 0) * 128 + c], wn1 = Wn[(k + 1) * 128 + c];
      float wn2 = Wn[(k + 2) * 128 + c], wn3 = Wn[(k + 3) * 128 + c];
#pragma unroll
      for (int r = 0; r < 4; ++r) {
        float4 iv = S4[(rh * 4 + r) * 64 + (k >> 2)];  // wave-uniform broadcast
        accs[r] = fmaf(iv.x, ws0, accs[r]); accs[r] = fmaf(iv.y, ws1, accs[r]);
        accs[r] = fmaf(iv.z, ws2, accs[r]); accs[r] = fmaf(iv.w, ws3, accs[r]);
        accn[r] = fmaf(iv.x, wn0, accn[r]); accn[r] = fmaf(iv.y, wn1, accn[r]);
        accn[r] = fmaf(iv.z, wn2, accn[r]); accn[r] = fmaf(iv.w, wn3, accn[r]);
      }
    }
    // Hs fp32 out
#pragma unroll
    for (int r = 0; r < 4; ++r)
      HsOut[(size_t)(i0 + rh * 4 + r) * 128 + c] = accs[r];
    // HnT bf16 out, j-block-major
    {
      union { unsigned short us[4]; ushort4 u4; } pk;
#pragma unroll
      for (int r = 0; r < 4; ++r) pk.us[r] = f2bf(accn[r]);
      *(ushort4*)(HnT + (size_t)(i0 >> 3) * 1024 + c * 8 + rh * 4) = pk.u4;
    }
    // fused reductions -> es = exp(s), en = exp(n)
    float* red = (float*)S4;  // 8 x 128 f32 within this unit's scratch
    const int wvl = tl >> 6, lnl = t & 63;
    __syncthreads();
    {
      float av = as_[c];
#pragma unroll
      for (int r = 0; r < 4; ++r) red[(rh * 4 + r) * 128 + c] = accs[r] * av;
    }
    __syncthreads();
#pragma unroll
    for (int h = 0; h < 2; ++h) {
      int row = wvl * 2 + h;
      float p = red[row * 128 + lnl] + red[row * 128 + 64 + lnl];
#pragma unroll
      for (int off = 32; off >= 1; off >>= 1) p += __shfl_down(p, off);
      if (lnl == 0) es_g[i0 + row] = __expf(p);
    }
    __syncthreads();
    {
      float av = an_[c];
#pragma unroll
      for (int r = 0; r < 4; ++r) red[(rh * 4 + r) * 128 + c] = accn[r] * av;
    }
    __syncthreads();
#pragma unroll
    for (int h = 0; h < 2; ++h) {
      int row = wvl * 2 + h;
      float p = red[row * 128 + lnl] + red[row * 128 + 64 + lnl];
#pragma unroll
      for (int off = 32; off >= 1; off >>= 1) p += __shfl_down(p, off);
      if (lnl == 0) en_g[i0 + row] = __expf(p);
    }
  };

  // parity phase order: half the machine streams HBM while half does VALU
  if ((bid & 1) == 0) { do_pack(); do_proj(); }
  else                { do_proj(); do_pack(); }

  __threadfence();
  cg::this_grid().sync();

  // ---------------- phase 2: R10-verified loop ----------------
  float* en_lds = (float*)smem;       // 32 KB (overwrites proj scratch)
  float* cmb = (float*)smem;          // 64 KB (epilogue; bits dead by then)

  const int wv = t >> 6;     // 0..15
  const int fp = wv >> 3;    // 0..1  f-half
  const int jp = wv & 7;     // 0..7  j-partition
  const int ln = t & 63;
  const int q = ln >> 4;     // k-slice within K=32
  const int m = ln & 15;     // B col / C col

  {
    float4* dst = (float4*)en_lds;
    const float4* s4 = (const float4*)en_g;
    dst[t] = s4[t];
    dst[t + 1024] = s4[t + 1024];
  }

  const float sme0 = es_g[row0 + m];
  const float sme1 = es_g[row0 + 16 + m];
  const unsigned short* bptr = HnT + ((size_t)(jp * 128 + q) * 128 + fp * 64 + m) * 8;
  const float* nvl = en_lds + jp * 1024 + q * 8;       // + tt*32
  const unsigned* bts = bits_lds + jp * 1024 + m;      // + tt*32 (+16 group1)

  f32x4 acc0[4], acc1[4];
#pragma unroll
  for (int ftl = 0; ftl < 4; ++ftl) {
    acc0[ftl] = (f32x4){0.f, 0.f, 0.f, 0.f};
    acc1[ftl] = (f32x4){0.f, 0.f, 0.f, 0.f};
  }
  float zp0 = 0.f, zp1 = 0.f;

  union Breg { uint4 u; short8 s; };
  Breg breg[4];

  __syncthreads();  // en staged; bits from phase 1 already resident

  breg[0].u = *(const uint4*)(bptr);
  breg[1].u = *(const uint4*)(bptr + 128);
  breg[2].u = *(const uint4*)(bptr + 256);
  breg[3].u = *(const uint4*)(bptr + 384);

#pragma unroll 2
  for (int tt = 0; tt < 32; ++tt) {
    short8 fr0, fr1;
    {
      float4 nv0 = *(const float4*)(nvl + tt * 32);
      float4 nv1 = *(const float4*)(nvl + tt * 32 + 4);
      const unsigned bw0 = bts[tt * 32];        // row m
      const unsigned bw1 = bts[tt * 32 + 16];   // row m+16
      const unsigned byte0 = (bw0 >> (q * 8)) & 0xffu;
      const unsigned byte1 = (bw1 >> (q * 8)) & 0xffu;
      float ev[8] = {nv0.x, nv0.y, nv0.z, nv0.w, nv1.x, nv1.y, nv1.z, nv1.w};
#pragma unroll
      for (int k = 0; k < 8; ++k) {
        float w0 = ((byte0 >> k) & 1u) ? fmaxf(sme0 * ev[k], 1.f) : 0.f;
        float w1 = ((byte1 >> k) & 1u) ? fmaxf(sme1 * ev[k], 1.f) : 0.f;
        zp0 += w0; zp1 += w1;
        fr0[k] = (short)f2bf(w0);
        fr1[k] = (short)f2bf(w1);
      }
    }
    __builtin_amdgcn_s_setprio(1);
    acc0[0] = __builtin_amdgcn_mfma_f32_16x16x32_bf16(fr0, breg[0].s, acc0[0], 0, 0, 0);
    acc1[0] = __builtin_amdgcn_mfma_f32_16x16x32_bf16(fr1, breg[0].s, acc1[0], 0, 0, 0);
    acc0[1] = __builtin_amdgcn_mfma_f32_16x16x32_bf16(fr0, breg[1].s, acc0[1], 0, 0, 0);
    acc1[1] = __builtin_amdgcn_mfma_f32_16x16x32_bf16(fr1, breg[1].s, acc1[1], 0, 0, 0);
    acc0[2] = __builtin_amdgcn_mfma_f32_16x16x32_bf16(fr0, breg[2].s, acc0[2], 0, 0, 0);
    acc1[2] = __builtin_amdgcn_mfma_f32_16x16x32_bf16(fr1, breg[2].s, acc1[2], 0, 0, 0);
    acc0[3] = __builtin_amdgcn_mfma_f32_16x16x32_bf16(fr0, breg[3].s, acc0[3], 0, 0, 0);
    acc1[3] = __builtin_amdgcn_mfma_f32_16x16x32_bf16(fr1, breg[3].s, acc1[3], 0, 0, 0);
    __builtin_amdgcn_s_setprio(0);
    // issue breg(tt+1), branch-free; tt=31 overruns into es/en region (discarded)
    {
      const unsigned short* p = bptr + (size_t)(tt + 1) * 4096;
      breg[0].u = *(const uint4*)(p);
      breg[1].u = *(const uint4*)(p + 128);
      breg[2].u = *(const uint4*)(p + 256);
      breg[3].u = *(const uint4*)(p + 384);
    }
  }

  // Z partials: w replicated across fp -> only fp==0 contributes
  {
    float zz0 = zp0, zz1 = zp1;
    zz0 += __shfl_down(zz0, 32); zz0 += __shfl_down(zz0, 16);
    zz1 += __shfl_down(zz1, 32); zz1 += __shfl_down(zz1, 16);
    if (fp == 0 && ln < 16) { zsh[jp][m] = zz0; zsh[jp][16 + m] = zz1; }
  }
  __syncthreads();  // loop LDS dead; zsh ready

  // epilogue tree (R10-verified layout: slot idx = g*1024 + (q*4+reg)*64 + ftl*16 + m)
#define DUMP_SLOT(S)                                                        \
  {                                                                         \
    float* d = cmb + (S) * 2048 + q * 256 + m;                              \
    _Pragma("unroll") for (int ftl = 0; ftl < 4; ++ftl)                     \
      _Pragma("unroll") for (int reg = 0; reg < 4; ++reg) {                 \
        d[reg * 64 + ftl * 16] = acc0[ftl][reg];                            \
        d[1024 + reg * 64 + ftl * 16] = acc1[ftl][reg];                     \
      }                                                                     \
  }
#define ADD_SLOT(S)                                                         \
  {                                                                         \
    const float* d = cmb + (S) * 2048 + q * 256 + m;                        \
    _Pragma("unroll") for (int ftl = 0; ftl < 4; ++ftl)                     \
      _Pragma("unroll") for (int reg = 0; reg < 4; ++reg) {                 \
        acc0[ftl][reg] += d[reg * 64 + ftl * 16];                           \
        acc1[ftl][reg] += d[1024 + reg * 64 + ftl * 16];                    \
      }                                                                     \
  }
  if (jp >= 4) DUMP_SLOT(fp * 4 + (jp - 4));
  __syncthreads();
  if (jp < 4) ADD_SLOT(fp * 4 + jp);
  if (t < 32) {
    float z = zsh[0][t] + zsh[1][t] + zsh[2][t] + zsh[3][t] +
              zsh[4][t] + zsh[5][t] + zsh[6][t] + zsh[7][t];
    zf[t] = 1.f / z;
  }
  __syncthreads();
  if (jp == 2 || jp == 3) DUMP_SLOT(fp * 2 + (jp - 2));
  __syncthreads();
  if (jp < 2) ADD_SLOT(fp * 2 + jp);
  __syncthreads();
  if (jp == 1) DUMP_SLOT(fp);
  __syncthreads();
  if (jp == 0) { ADD_SLOT(fp); DUMP_SLOT(fp); }
  __syncthreads();
#undef DUMP_SLOT
#undef ADD_SLOT

  // final coalesced write: out = elu(0.5*h_s + acc/Z)
  {
    const int row = t >> 5;        // 0..31
    const int f0 = (t & 31) * 4;   // 0..124
    const int fpx = f0 >> 6;
    f32x4 ssum = *(const f32x4*)&cmb[fpx * 2048 + row * 64 + (f0 & 63)];
    const float invz = zf[row];
    const size_t off = (size_t)(row0 + row) * 128 + f0;
    float4 h = *(const float4*)(HsOut + off);
    float4 o;
    o.x = eluf(fmaf(ssum[0], invz, 0.5f * h.x));
    o.y = eluf(fmaf(ssum[1], invz, 0.5f * h.y));
    o.z = eluf(fmaf(ssum[2], invz, 0.5f * h.z));
    o.w = eluf(fmaf(ssum[3], invz, 0.5f * h.w));
    *(float4*)(HsOut + off) = o;
  }
}

// ================= Fallback path (R10-verified two-kernel) =================
__global__ __launch_bounds__(256) void k_pre(const float* __restrict__ X,
                                             const int* __restrict__ A,
                                             const float* __restrict__ Ws,
                                             const float* __restrict__ Wn,
                                             const float* __restrict__ as_,
                                             const float* __restrict__ an_,
                                             float* __restrict__ Hs,
                                             unsigned short* __restrict__ HnT,
                                             float* __restrict__ es_out,
                                             float* __restrict__ en_out,
                                             unsigned* __restrict__ P) {
  __shared__ float4 lin4[8 * 64];
  const int bid = blockIdx.x;
  const int q5 = bid / 5, r5 = bid - q5 * 5;
  const int t = threadIdx.x;

  if (r5 == 4) {
    const int row0 = q5 * 32;
#pragma unroll 1
    for (int k = 0; k < 32; ++k) {
      int g = t + k * 256;
      int rr = g >> 8;
      int c8 = g & 255;
      const int4* src = (const int4*)(A + (size_t)(row0 + rr) * NN + c8 * 32);
      int4 v0 = src[0], v1 = src[1], v2 = src[2], v3 = src[3];
      int4 v4 = src[4], v5 = src[5], v6 = src[6], v7 = src[7];
      unsigned w = pack4(v0, 0)  | pack4(v1, 4)  | pack4(v2, 8)  | pack4(v3, 12) |
                   pack4(v4, 16) | pack4(v5, 20) | pack4(v6, 24) | pack4(v7, 28);
      P[(size_t)(row0 + rr) * 256 + c8] = w;
    }
    return;
  }

  const int i0 = (q5 * 4 + r5) * 8;
  const float4* Xg = (const float4*)X + (size_t)i0 * 64;
  lin4[t] = Xg[t];
  lin4[t + 256] = Xg[t + 256];
  __syncthreads();
  const int c = t & 127;
  const int rh = t >> 7;
  float accs[4], accn[4];
#pragma unroll
  for (int r = 0; r < 4; ++r) { accs[r] = 0.f; accn[r] = 0.f; }
  for (int k = 0; k < 256; k += 4) {
    float ws0 = Ws[(k + 0) * 128 + c], ws1 = Ws[(k + 1) * 128 + c];
    float ws2 = Ws[(k + 2) * 128 + c], ws3 = Ws[(k + 3) * 128 + c];
    float wn0 = Wn[(k + 0) * 128 + c], wn1 = Wn[(k + 1) * 128 + c];
    float wn2 = Wn[(k + 2) * 128 + c], wn3 = Wn[(k + 3) * 128 + c];
#pragma unroll
    for (int r = 0; r < 4; ++r) {
      float4 iv = lin4[(rh * 4 + r) * 64 + (k >> 2)];
      accs[r] = fmaf(iv.x, ws0, accs[r]); accs[r] = fmaf(iv.y, ws1, accs[r]);
      accs[r] = fmaf(iv.z, ws2, accs[r]); accs[r] = fmaf(iv.w, ws3, accs[r]);
      accn[r] = fmaf(iv.x, wn0, accn[r]); accn[r] = fmaf(iv.y, wn1, accn[r]);
      accn[r] = fmaf(iv.z, wn2, accn[r]); accn[r] = fmaf(iv.w, wn3, accn[r]);
    }
  }
#pragma unroll
  for (int r = 0; r < 4; ++r)
    Hs[(size_t)(i0 + rh * 4 + r) * 128 + c] = accs[r];
  {
    union { unsigned short us[4]; ushort4 u4; } pk;
#pragma unroll
    for (int r = 0; r < 4; ++r) pk.us[r] = f2bf(accn[r]);
    *(ushort4*)(HnT + (size_t)(i0 >> 3) * 1024 + c * 8 + rh * 4) = pk.u4;
  }
  float* red = (float*)lin4;
  const int wv = t >> 6, ln = t & 63;
  __syncthreads();
  {
    float av = as_[c];
#pragma unroll
    for (int r = 0; r < 4; ++r) red[(rh * 4 + r) * 128 + c] = accs[r] * av;
  }
  __syncthreads();
#pragma unroll
  for (int h = 0; h < 2; ++h) {
    int row = wv * 2 + h;
    float p = red[row * 128 + ln] + red[row * 128 + 64 + ln];
#pragma unroll
    for (int off = 32; off >= 1; off >>= 1) p += __shfl_down(p, off);
    if (ln == 0) es_out[i0 + row] = __expf(p);
  }
  __syncthreads();
  {
    float av = an_[c];
#pragma unroll
    for (int r = 0; r < 4; ++r) red[(rh * 4 + r) * 128 + c] = accn[r] * av;
  }
  __syncthreads();
#pragma unroll
  for (int h = 0; h < 2; ++h) {
    int row = wv * 2 + h;
    float p = red[row * 128 + ln] + red[row * 128 + 64 + ln];
#pragma unroll
    for (int off = 32; off >= 1; off >>= 1) p += __shfl_down(p, off);
    if (ln == 0) en_out[i0 + row] = __expf(p);
  }
}

__global__ __launch_bounds__(1024, 4) void k_main(const unsigned* __restrict__ Pk,
                                                  const unsigned short* __restrict__ HnT,
                                                  const float* __restrict__ es_g,
                                                  const float* __restrict__ en_g,
                                                  float* __restrict__ HsOut) {
  __shared__ __align__(16) char smem[65536];
  float* en_lds = (float*)smem;
  unsigned* bits_lds = (unsigned*)(smem + 32768);
  float* cmb = (float*)smem;
  __shared__ float zsh[8][32];
  __shared__ float zf[32];

  const int t = threadIdx.x;
  const int wv = t >> 6;
  const int fp = wv >> 3;
  const int jp = wv & 7;
  const int ln = t & 63;
  const int q = ln >> 4;
  const int m = ln & 15;
  const int row0 = blockIdx.x * 32;

  {
    float4* dst = (float4*)en_lds;
    const float4* s4 = (const float4*)en_g;
    dst[t] = s4[t];
    dst[t + 1024] = s4[t + 1024];
#pragma unroll
    for (int k = 0; k < 8; ++k) {
      int g = t + k * 1024;
      int rr = g >> 8;
      int c8 = g & 255;
      unsigned w = Pk[(size_t)(row0 + rr) * 256 + c8];
      bits_lds[(c8 >> 5) * 1024 + (c8 & 31) * 32 + rr] = w;
    }
  }

  const float sme0 = es_g[row0 + m];
  const float sme1 = es_g[row0 + 16 + m];
  const unsigned short* bptr = HnT + ((size_t)(jp * 128 + q) * 128 + fp * 64 + m) * 8;
  const float* nvl = en_lds + jp * 1024 + q * 8;
  const unsigned* bts = bits_lds + jp * 1024 + m;

  f32x4 acc0[4], acc1[4];
#pragma unroll
  for (int ftl = 0; ftl < 4; ++ftl) {
    acc0[ftl] = (f32x4){0.f, 0.f, 0.f, 0.f};
    acc1[ftl] = (f32x4){0.f, 0.f, 0.f, 0.f};
  }
  float zp0 = 0.f, zp1 = 0.f;

  union Breg { uint4 u; short8 s; };
  Breg breg[4];

  __syncthreads();

  breg[0].u = *(const uint4*)(bptr);
  breg[1].u = *(const uint4*)(bptr + 128);
  breg[2].u = *(const uint4*)(bptr + 256);
  breg[3].u = *(const uint4*)(bptr + 384);

#pragma unroll 2
  for (int tt = 0; tt < 32; ++tt) {
    short8 fr0, fr1;
    {
      float4 nv0 = *(const float4*)(nvl + tt * 32);
      float4 nv1 = *(const float4*)(nvl + tt * 32 + 4);
      const unsigned bw0 = bts[tt * 32];
      const unsigned bw1 = bts[tt * 32 + 16];
      const unsigned byte0 = (bw0 >> (q * 8)) & 0xffu;
      const unsigned byte1 = (bw1 >> (q * 8)) & 0xffu;
      float ev[8] = {nv0.x, nv0.y, nv0.z, nv0.w, nv1.x, nv1.y, nv1.z, nv1.w};
#pragma unroll
      for (int k = 0; k < 8; ++k) {
        float w0 = ((byte0 >> k) & 1u) ? fmaxf(sme0 * ev[k], 1.f) : 0.f;
        float w1 = ((byte1 >> k) & 1u) ? fmaxf(sme1 * ev[k], 1.f) : 0.f;
        zp0 += w0; zp1 += w1;
        fr0[k] = (short)f2bf(w0);
        fr1[k] = (short)f2bf(w1);
      }
    }
    __builtin_amdgcn_s_setprio(1);
    acc0[0] = __builtin_amdgcn_mfma_f32_16x16x32_bf16(fr0, breg[0].s, acc0[0], 0, 0, 0);
    acc1[0] = __builtin_amdgcn_mfma_f32_16x16x32_bf16(fr1, breg[0].s, acc1[0], 0, 0, 0);
    acc0[1] = __builtin_amdgcn_mfma_f32_16x16x32_bf16(fr0, breg[1].s, acc0[1], 0, 0, 0);
    acc1[1] = __builtin_amdgcn_mfma_f32_16x16x32_bf16(fr1, breg[1].s, acc1[1], 0, 0, 0);
    acc0[2] = __builtin_amdgcn_mfma_f32_16x16x32_bf16(fr0, breg[2].s, acc0[2], 0, 0, 0);
    acc1[2] = __builtin_amdgcn_mfma_f32_16x16x32_bf16(fr1, breg[2].s, acc1[2], 0, 0, 0);
    acc0[3] = __builtin_amdgcn_mfma_f32_16x16x32_bf16(fr0, breg[3].s, acc0[3], 0, 0, 0);
    acc1[3] = __builtin_amdgcn_mfma_f32_16x16x32_bf16(fr1, breg[3].s, acc1[3], 0, 0, 0);
    __builtin_amdgcn_s_setprio(0);
    {
      const unsigned short* p = bptr + (size_t)(tt + 1) * 4096;
      breg[0].u = *(const uint4*)(p);
      breg[1].u = *(const uint4*)(p + 128);
      breg[2].u = *(const uint4*)(p + 256);
      breg[3].u = *(const uint4*)(p + 384);
    }
  }

  {
    float zz0 = zp0, zz1 = zp1;
    zz0 += __shfl_down(zz0, 32); zz0 += __shfl_down(zz0, 16);
    zz1 += __shfl_down(zz1, 32); zz1 += __shfl_down(zz1, 16);
    if (fp == 0 && ln < 16) { zsh[jp][m] = zz0; zsh[jp][16 + m] = zz1; }
  }
  __syncthreads();

#define DUMP_SLOT(S)                                                        \
  {                                                                         \
    float* d = cmb + (S) * 2048 + q * 256 + m;                              \
    _Pragma("unroll") for (int ftl = 0; ftl < 4; ++ftl)                     \
      _Pragma("unroll") for (int reg = 0; reg < 4; ++reg) {                 \
        d[reg * 64 + ftl * 16] = acc0[ftl][reg];                            \
        d[1024 + reg * 64 + ftl * 16] = acc1[ftl][reg];                     \
      }                                                                     \
  }
#define ADD_SLOT(S)                                                         \
  {                                                                         \
    const float* d = cmb + (S) * 2048 + q * 256 + m;                        \
    _Pragma("unroll") for (int ftl = 0; ftl < 4; ++ftl)                     \
      _Pragma("unroll") for (int reg = 0; reg < 4; ++reg) {                 \
        acc0[ftl][reg] += d[reg * 64 + ftl * 16];                           \
        acc1[ftl][reg] += d[1024 + reg * 64 + ftl * 16];                    \
      }                                                                     \
  }
  if (jp >= 4) DUMP_SLOT(fp * 4 + (jp - 4));
  __syncthreads();
  if (jp < 4) ADD_SLOT(fp * 4 + jp);
  if (t < 32) {
    float z = zsh[0][t] + zsh[1][t] + zsh[2][t] + zsh[3][t] +
              zsh[4][t] + zsh[5][t] + zsh[6][t] + zsh[7][t];
    zf[t] = 1.f / z;
  }
  __syncthreads();
  if (jp == 2 || jp == 3) DUMP_SLOT(fp * 2 + (jp - 2));
  __syncthreads();
  if (jp < 2) ADD_SLOT(fp * 2 + jp);
  __syncthreads();
  if (jp == 1) DUMP_SLOT(fp);
  __syncthreads();
  if (jp == 0) { ADD_SLOT(fp); DUMP_SLOT(fp); }
  __syncthreads();
#undef DUMP_SLOT
#undef ADD_SLOT

  {
    const int row = t >> 5;
    const int f0 = (t & 31) * 4;
    const int fpx = f0 >> 6;
    f32x4 ssum = *(const f32x4*)&cmb[fpx * 2048 + row * 64 + (f0 & 63)];
    const float invz = zf[row];
    const size_t off = (size_t)(row0 + row) * 128 + f0;
    float4 h = *(const float4*)(HsOut + off);
    float4 o;
    o.x = eluf(fmaf(ssum[0], invz, 0.5f * h.x));
    o.y = eluf(fmaf(ssum[1], invz, 0.5f * h.y));
    o.z = eluf(fmaf(ssum[2], invz, 0.5f * h.z));
    o.w = eluf(fmaf(ssum[3], invz, 0.5f * h.w));
    *(float4*)(HsOut + off) = o;
  }
}

extern "C" void kernel_launch(void* const* d_in, const int* in_sizes, int n_in,
                              void* d_out, int out_size, void* d_ws, size_t ws_size,
                              hipStream_t stream) {
  const float* X   = (const float*)d_in[0];
  const int*   A   = (const int*)d_in[1];
  const float* Ws  = (const float*)d_in[2];
  const float* as_ = (const float*)d_in[3];
  const float* Wn  = (const float*)d_in[4];
  const float* an_ = (const float*)d_in[5];
  float* out = (float*)d_out;  // holds h_s, then final output (in-place epilogue)

  unsigned short* HnT = (unsigned short*)d_ws;       // 2 MB (j-block-major)
  float* es = (float*)(HnT + (size_t)128 * NN);      // 8192 f32 = exp(s)
  float* en = es + NN;                               // 8192 f32 = exp(n)
  unsigned* P = (unsigned*)(en + NN);                // 8 MB bitmask (fallback only)

  void* ka[] = {(void*)&X, (void*)&A, (void*)&Ws, (void*)&Wn, (void*)&as_,
                (void*)&an_, (void*)&out, (void*)&HnT, (void*)&es, (void*)&en};
  hipError_t err = hipLaunchCooperativeKernel((const void*)k_fused, dim3(256),
                                              dim3(1024), ka, 0, stream);
  if (err != hipSuccess) {
    // fallback: R10-verified two-kernel path
    k_pre<<<1280, 256, 0, stream>>>(X, A, Ws, Wn, as_, an_, out, HnT, es, en, P);
    k_main<<<256, 1024, 0, stream>>>(P, HnT, es, en, out);
  }
}

// Round 13
// 447.731 us; speedup vs baseline: 1.4059x; 1.4059x over previous
//
#include <hip/hip_runtime.h>
#include <math.h>

#define NN 8192
// out = elu(0.5*h_s + (sum_j w_ij h_n_j)/Z_i), w_ij = adj_ij * exp(relu(s_i+n_j))
// Factorization: exp(relu(s+n)) = max(exp(s)*exp(n), 1) (exp monotone) ->
// precompute es=exp(s), en=exp(n); NO transcendental in the O(N^2) loop.

typedef short short8 __attribute__((ext_vector_type(8)));   // 8 bf16 (4 VGPRs)
typedef float f32x4 __attribute__((ext_vector_type(4)));

__device__ __forceinline__ float eluf(float x) {
  return x > 0.f ? x : (__expf(x) - 1.f);
}
__device__ __forceinline__ unsigned short f2bf(float f) {
  union { float f; unsigned u; } v; v.f = f;
  unsigned r = v.u + 0x7fffu + ((v.u >> 16) & 1u);  // RNE
  return (unsigned short)(r >> 16);
}
__device__ __forceinline__ unsigned pack4(int4 v, int sh) {
  return ((unsigned)(v.x & 1) << sh) | ((unsigned)(v.y & 1) << (sh + 1)) |
         ((unsigned)(v.z & 1) << (sh + 2)) | ((unsigned)(v.w & 1) << (sh + 3));
}

// ---------------- Kernel 1: fused {projections+reductions | adj bit-pack} ----
// R7/R10-verified, unchanged. Grid 1280 x 256. Role by blockIdx%5.
__global__ __launch_bounds__(256) void k_pre(const float* __restrict__ X,
                                             const int* __restrict__ A,
                                             const float* __restrict__ Ws,
                                             const float* __restrict__ Wn,
                                             const float* __restrict__ as_,
                                             const float* __restrict__ an_,
                                             float* __restrict__ Hs,
                                             unsigned short* __restrict__ HnT,
                                             float* __restrict__ es_out,
                                             float* __restrict__ en_out,
                                             unsigned* __restrict__ P) {
  __shared__ float4 lin4[8 * 64];  // 8 KB (proj role only)
  const int bid = blockIdx.x;
  const int q5 = bid / 5, r5 = bid - q5 * 5;
  const int t = threadIdx.x;

  if (r5 == 4) {
    const int row0 = q5 * 32;
#pragma unroll 1
    for (int k = 0; k < 32; ++k) {
      int g = t + k * 256;
      int rr = g >> 8;
      int c8 = g & 255;
      const int4* src = (const int4*)(A + (size_t)(row0 + rr) * NN + c8 * 32);
      int4 v0 = src[0], v1 = src[1], v2 = src[2], v3 = src[3];
      int4 v4 = src[4], v5 = src[5], v6 = src[6], v7 = src[7];
      unsigned w = pack4(v0, 0)  | pack4(v1, 4)  | pack4(v2, 8)  | pack4(v3, 12) |
                   pack4(v4, 16) | pack4(v5, 20) | pack4(v6, 24) | pack4(v7, 28);
      P[(size_t)(row0 + rr) * 256 + c8] = w;
    }
    return;
  }

  const int i0 = (q5 * 4 + r5) * 8;
  const float4* Xg = (const float4*)X + (size_t)i0 * 64;
  lin4[t] = Xg[t];
  lin4[t + 256] = Xg[t + 256];
  __syncthreads();
  const int c = t & 127;
  const int rh = t >> 7;
  float accs[4], accn[4];
#pragma unroll
  for (int r = 0; r < 4; ++r) { accs[r] = 0.f; accn[r] = 0.f; }
  for (int k = 0; k < 256; k += 4) {
    float ws0 = Ws[(k + 0) * 128 + c], ws1 = Ws[(k + 1) * 128 + c];
    float ws2 = Ws[(k + 2) * 128 + c], ws3 = Ws[(k + 3) * 128 + c];
    float wn0 = Wn[(k + 0) * 128 + c], wn1 = Wn[(k + 1) * 128 + c];
    float wn2 = Wn[(k + 2) * 128 + c], wn3 = Wn[(k + 3) * 128 + c];
#pragma unroll
    for (int r = 0; r < 4; ++r) {
      float4 iv = lin4[(rh * 4 + r) * 64 + (k >> 2)];
      accs[r] = fmaf(iv.x, ws0, accs[r]); accs[r] = fmaf(iv.y, ws1, accs[r]);
      accs[r] = fmaf(iv.z, ws2, accs[r]); accs[r] = fmaf(iv.w, ws3, accs[r]);
      accn[r] = fmaf(iv.x, wn0, accn[r]); accn[r] = fmaf(iv.y, wn1, accn[r]);
      accn[r] = fmaf(iv.z, wn2, accn[r]); accn[r] = fmaf(iv.w, wn3, accn[r]);
    }
  }
#pragma unroll
  for (int r = 0; r < 4; ++r)
    Hs[(size_t)(i0 + rh * 4 + r) * 128 + c] = accs[r];
  {
    union { unsigned short us[4]; ushort4 u4; } pk;
#pragma unroll
    for (int r = 0; r < 4; ++r) pk.us[r] = f2bf(accn[r]);
    *(ushort4*)(HnT + (size_t)(i0 >> 3) * 1024 + c * 8 + rh * 4) = pk.u4;
  }
  float* red = (float*)lin4;
  const int wv = t >> 6, ln = t & 63;
  __syncthreads();
  {
    float av = as_[c];
#pragma unroll
    for (int r = 0; r < 4; ++r) red[(rh * 4 + r) * 128 + c] = accs[r] * av;
  }
  __syncthreads();
#pragma unroll
  for (int h = 0; h < 2; ++h) {
    int row = wv * 2 + h;
    float p = red[row * 128 + ln] + red[row * 128 + 64 + ln];
#pragma unroll
    for (int off = 32; off >= 1; off >>= 1) p += __shfl_down(p, off);
    if (ln == 0) es_out[i0 + row] = __expf(p);
  }
  __syncthreads();
  {
    float av = an_[c];
#pragma unroll
    for (int r = 0; r < 4; ++r) red[(rh * 4 + r) * 128 + c] = accn[r] * av;
  }
  __syncthreads();
#pragma unroll
  for (int h = 0; h < 2; ++h) {
    int row = wv * 2 + h;
    float p = red[row * 128 + ln] + red[row * 128 + 64 + ln];
#pragma unroll
    for (int off = 32; off >= 1; off >>= 1) p += __shfl_down(p, off);
    if (ln == 0) en_out[i0 + row] = __expf(p);
  }
}

// ---------------- Kernel 2: attention GEMM + softmax + elu ----------------
// R10-verified geometry (32 rows/block, block 1024 = 2 f-halves x 8 j-parts,
// grid 256, 1 block/CU) with ONE change: 2-generation breg double-buffer
// using named bregA/bregB and an explicit 2-iteration body (compile-time
// parity, the R1-verified non-spilling pattern). Issue B(tt+1) at chunk top
// (covered by fr(tt)+MFMA(tt) ~400cy), A(tt+2) mid-chunk (~600cy cover);
// FIFO gives counted vmcnt(4) at each MFMA, never a full drain. Numerics
// identical to R10 (same accumulation order).
__global__ __launch_bounds__(1024, 4) void k_main(const unsigned* __restrict__ Pk,
                                                  const unsigned short* __restrict__ HnT,
                                                  const float* __restrict__ es_g,
                                                  const float* __restrict__ en_g,
                                                  float* __restrict__ HsOut) {
  __shared__ __align__(16) char smem[65536];           // 64 KB
  float* en_lds = (float*)smem;                        // 8192 f32 = 32 KB (loop)
  unsigned* bits_lds = (unsigned*)(smem + 32768);      // 8192 u32 = 32 KB (loop)
  float* cmb = (float*)smem;                           // 16384 f32 (epilogue tree)
  __shared__ float zsh[8][32];
  __shared__ float zf[32];

  const int t = threadIdx.x;
  const int wv = t >> 6;     // 0..15
  const int fp = wv >> 3;    // 0..1  f-half (f-tiles fp*4 .. fp*4+3)
  const int jp = wv & 7;     // 0..7  j-partition (1024 cols each)
  const int ln = t & 63;
  const int q = ln >> 4;     // k-slice within K=32
  const int m = ln & 15;     // B col / C col (f = fp*64 + ftl*16 + m)
  const int row0 = blockIdx.x * 32;

  // ---- prologue: stage en (8192 f32) and bits for 32 rows (8192 u32) ----
  {
    float4* dst = (float4*)en_lds;
    const float4* s4 = (const float4*)en_g;
    dst[t] = s4[t];
    dst[t + 1024] = s4[t + 1024];
#pragma unroll
    for (int k = 0; k < 8; ++k) {
      int g = t + k * 1024;           // 0..8191
      int rr = g >> 8;                // row-in-block 0..31
      int c8 = g & 255;               // word-in-row (= j/32)
      unsigned w = Pk[(size_t)(row0 + rr) * 256 + c8];
      // LDS layout [jp][tt][32 rows]
      bits_lds[(c8 >> 5) * 1024 + (c8 & 31) * 32 + rr] = w;
    }
  }

  const float sme0 = es_g[row0 + m];
  const float sme1 = es_g[row0 + 16 + m];
  // HnT elem(jb, f, ji) at jb*1024 + f*8 + ji ; jb = jp*128 + q (+ tt*4),
  // f = fp*64 + ftl*16 + m
  const unsigned short* bptr = HnT + ((size_t)(jp * 128 + q) * 128 + fp * 64 + m) * 8;
  const float* nvl = en_lds + jp * 1024 + q * 8;       // + tt*32
  const unsigned* bts = bits_lds + jp * 1024 + m;      // + tt*32 (+16 group1)

  f32x4 acc0[4], acc1[4];
#pragma unroll
  for (int ftl = 0; ftl < 4; ++ftl) {
    acc0[ftl] = (f32x4){0.f, 0.f, 0.f, 0.f};
    acc1[ftl] = (f32x4){0.f, 0.f, 0.f, 0.f};
  }
  float zp0 = 0.f, zp1 = 0.f;

  union Breg { uint4 u; short8 s; };
  Breg bregA[4], bregB[4];

  __syncthreads();  // LDS stage complete

  // gen(0) -> A
  bregA[0].u = *(const uint4*)(bptr);
  bregA[1].u = *(const uint4*)(bptr + 128);
  bregA[2].u = *(const uint4*)(bptr + 256);
  bregA[3].u = *(const uint4*)(bptr + 384);

  // per-chunk A-frag compute (identical numerics to R10)
#define FRAGS(TT, FR0, FR1)                                                 \
  {                                                                         \
    float4 nv0 = *(const float4*)(nvl + (TT) * 32);                         \
    float4 nv1 = *(const float4*)(nvl + (TT) * 32 + 4);                     \
    const unsigned bw0 = bts[(TT) * 32];                                    \
    const unsigned bw1 = bts[(TT) * 32 + 16];                               \
    const unsigned byte0 = (bw0 >> (q * 8)) & 0xffu;                        \
    const unsigned byte1 = (bw1 >> (q * 8)) & 0xffu;                        \
    float ev[8] = {nv0.x, nv0.y, nv0.z, nv0.w, nv1.x, nv1.y, nv1.z, nv1.w}; \
    _Pragma("unroll") for (int k = 0; k < 8; ++k) {                         \
      float w0 = ((byte0 >> k) & 1u) ? fmaxf(sme0 * ev[k], 1.f) : 0.f;      \
      float w1 = ((byte1 >> k) & 1u) ? fmaxf(sme1 * ev[k], 1.f) : 0.f;      \
      zp0 += w0; zp1 += w1;                                                 \
      FR0[k] = (short)f2bf(w0);                                             \
      FR1[k] = (short)f2bf(w1);                                             \
    }                                                                       \
  }
#define MFMA8(FR0, FR1, BR)                                                 \
  __builtin_amdgcn_s_setprio(1);                                            \
  acc0[0] = __builtin_amdgcn_mfma_f32_16x16x32_bf16(FR0, BR[0].s, acc0[0], 0, 0, 0); \
  acc1[0] = __builtin_amdgcn_mfma_f32_16x16x32_bf16(FR1, BR[0].s, acc1[0], 0, 0, 0); \
  acc0[1] = __builtin_amdgcn_mfma_f32_16x16x32_bf16(FR0, BR[1].s, acc0[1], 0, 0, 0); \
  acc1[1] = __builtin_amdgcn_mfma_f32_16x16x32_bf16(FR1, BR[1].s, acc1[1], 0, 0, 0); \
  acc0[2] = __builtin_amdgcn_mfma_f32_16x16x32_bf16(FR0, BR[2].s, acc0[2], 0, 0, 0); \
  acc1[2] = __builtin_amdgcn_mfma_f32_16x16x32_bf16(FR1, BR[2].s, acc1[2], 0, 0, 0); \
  acc0[3] = __builtin_amdgcn_mfma_f32_16x16x32_bf16(FR0, BR[3].s, acc0[3], 0, 0, 0); \
  acc1[3] = __builtin_amdgcn_mfma_f32_16x16x32_bf16(FR1, BR[3].s, acc1[3], 0, 0, 0); \
  __builtin_amdgcn_s_setprio(0);

#pragma unroll 1
  for (int tt = 0; tt < 32; tt += 2) {
    // ---- issue gen(tt+1) -> B : covered by fr(tt) + MFMA(tt) ----
    {
      const unsigned short* p = bptr + (size_t)(tt + 1) * 4096;
      bregB[0].u = *(const uint4*)(p);
      bregB[1].u = *(const uint4*)(p + 128);
      bregB[2].u = *(const uint4*)(p + 256);
      bregB[3].u = *(const uint4*)(p + 384);
    }
    short8 fr0e, fr1e;
    FRAGS(tt, fr0e, fr1e)
    MFMA8(fr0e, fr1e, bregA)            // waits vmcnt(4): B stays in flight
    // ---- issue gen(tt+2) -> A ; tt=30 -> gen 32 overruns ~8 KB into the
    // es workspace region (read-only, discarded) ----
    {
      const unsigned short* p = bptr + (size_t)(tt + 2) * 4096;
      bregA[0].u = *(const uint4*)(p);
      bregA[1].u = *(const uint4*)(p + 128);
      bregA[2].u = *(const uint4*)(p + 256);
      bregA[3].u = *(const uint4*)(p + 384);
    }
    short8 fr0o, fr1o;
    FRAGS(tt + 1, fr0o, fr1o)
    MFMA8(fr0o, fr1o, bregB)            // waits vmcnt(4): A' stays in flight
  }
#undef FRAGS
#undef MFMA8

  // ---- Z partials: w replicated across fp -> only fp==0 contributes ----
  {
    float zz0 = zp0, zz1 = zp1;
    zz0 += __shfl_down(zz0, 32); zz0 += __shfl_down(zz0, 16);
    zz1 += __shfl_down(zz1, 32); zz1 += __shfl_down(zz1, 16);
    if (fp == 0 && ln < 16) { zsh[jp][m] = zz0; zsh[jp][16 + m] = zz1; }
  }
  __syncthreads();  // loop LDS dead; zsh ready

  // ---- epilogue tree (R10-verified layout: idx = g*1024 + (q*4+reg)*64 + ftl*16 + m) ----
#define DUMP_SLOT(S)                                                        \
  {                                                                         \
    float* d = cmb + (S) * 2048 + q * 256 + m;                              \
    _Pragma("unroll") for (int ftl = 0; ftl < 4; ++ftl)                     \
      _Pragma("unroll") for (int reg = 0; reg < 4; ++reg) {                 \
        d[reg * 64 + ftl * 16] = acc0[ftl][reg];                            \
        d[1024 + reg * 64 + ftl * 16] = acc1[ftl][reg];                     \
      }                                                                     \
  }
#define ADD_SLOT(S)                                                         \
  {                                                                         \
    const float* d = cmb + (S) * 2048 + q * 256 + m;                        \
    _Pragma("unroll") for (int ftl = 0; ftl < 4; ++ftl)                     \
      _Pragma("unroll") for (int reg = 0; reg < 4; ++reg) {                 \
        acc0[ftl][reg] += d[reg * 64 + ftl * 16];                           \
        acc1[ftl][reg] += d[1024 + reg * 64 + ftl * 16];                    \
      }                                                                     \
  }
  if (jp >= 4) DUMP_SLOT(fp * 4 + (jp - 4));
  __syncthreads();
  if (jp < 4) ADD_SLOT(fp * 4 + jp);
  if (t < 32) {
    float z = zsh[0][t] + zsh[1][t] + zsh[2][t] + zsh[3][t] +
              zsh[4][t] + zsh[5][t] + zsh[6][t] + zsh[7][t];
    zf[t] = 1.f / z;
  }
  __syncthreads();
  if (jp == 2 || jp == 3) DUMP_SLOT(fp * 2 + (jp - 2));
  __syncthreads();
  if (jp < 2) ADD_SLOT(fp * 2 + jp);
  __syncthreads();
  if (jp == 1) DUMP_SLOT(fp);
  __syncthreads();
  if (jp == 0) { ADD_SLOT(fp); DUMP_SLOT(fp); }
  __syncthreads();
#undef DUMP_SLOT
#undef ADD_SLOT

  // ---- final coalesced write: out = elu(0.5*h_s + acc/Z) ----
  {
    const int row = t >> 5;        // 0..31
    const int f0 = (t & 31) * 4;   // 0..124
    const int fpx = f0 >> 6;
    f32x4 ssum = *(const f32x4*)&cmb[fpx * 2048 + row * 64 + (f0 & 63)];
    const float invz = zf[row];
    const size_t off = (size_t)(row0 + row) * 128 + f0;
    float4 h = *(const float4*)(HsOut + off);
    float4 o;
    o.x = eluf(fmaf(ssum[0], invz, 0.5f * h.x));
    o.y = eluf(fmaf(ssum[1], invz, 0.5f * h.y));
    o.z = eluf(fmaf(ssum[2], invz, 0.5f * h.z));
    o.w = eluf(fmaf(ssum[3], invz, 0.5f * h.w));
    *(float4*)(HsOut + off) = o;
  }
}

extern "C" void kernel_launch(void* const* d_in, const int* in_sizes, int n_in,
                              void* d_out, int out_size, void* d_ws, size_t ws_size,
                              hipStream_t stream) {
  const float* X   = (const float*)d_in[0];
  const int*   A   = (const int*)d_in[1];
  const float* Ws  = (const float*)d_in[2];
  const float* as_ = (const float*)d_in[3];
  const float* Wn  = (const float*)d_in[4];
  const float* an_ = (const float*)d_in[5];
  float* out = (float*)d_out;  // holds h_s, then final output (in-place epilogue)

  unsigned short* HnT = (unsigned short*)d_ws;       // 2 MB (j-block-major)
  float* es = (float*)(HnT + (size_t)128 * NN);      // 8192 f32 = exp(s)
  float* en = es + NN;                               // 8192 f32 = exp(n)
  unsigned* P = (unsigned*)(en + NN);                // 8 MB bitmask (ws is 1 GiB)

  k_pre<<<1280, 256, 0, stream>>>(X, A, Ws, Wn, as_, an_, out, HnT, es, en, P);
  k_main<<<256, 1024, 0, stream>>>(P, HnT, es, en, out);
}

// Round 14
// 421.326 us; speedup vs baseline: 1.4941x; 1.0627x over previous
//
#include <hip/hip_runtime.h>
#include <math.h>

#define NN 8192
// out = elu(0.5*h_s + (sum_j w_ij h_n_j)/Z_i), w_ij = adj_ij * exp(relu(s_i+n_j))
// Factorization: exp(relu(s+n)) = max(exp(s)*exp(n), 1) (exp monotone) ->
// precompute es=exp(s), en=exp(n); NO transcendental in the O(N^2) loop.

typedef short short8 __attribute__((ext_vector_type(8)));   // 8 bf16 (4 VGPRs)
typedef float f32x4 __attribute__((ext_vector_type(4)));

__device__ __forceinline__ float eluf(float x) {
  return x > 0.f ? x : (__expf(x) - 1.f);
}
__device__ __forceinline__ unsigned short f2bf(float f) {
  union { float f; unsigned u; } v; v.f = f;
  unsigned r = v.u + 0x7fffu + ((v.u >> 16) & 1u);  // RNE
  return (unsigned short)(r >> 16);
}
__device__ __forceinline__ unsigned pack4(int4 v, int sh) {
  return ((unsigned)(v.x & 1) << sh) | ((unsigned)(v.y & 1) << (sh + 1)) |
         ((unsigned)(v.z & 1) << (sh + 2)) | ((unsigned)(v.w & 1) << (sh + 3));
}

// ---------------- Kernel 1: fused {projections+reductions | adj bit-pack} ----
// Verified at 418.3 (R6 source). Grid 1280 x 256. Role by blockIdx%5: every
// 5th block streams 32 adj rows -> bitmask P (256 blocks, HBM-bound); the
// rest run the proj body (1024 blocks, VALU-bound). Interleaved roles
// co-execute, hiding proj's compute under pack's HBM stream.
__global__ __launch_bounds__(256) void k_pre(const float* __restrict__ X,
                                             const int* __restrict__ A,
                                             const float* __restrict__ Ws,
                                             const float* __restrict__ Wn,
                                             const float* __restrict__ as_,
                                             const float* __restrict__ an_,
                                             float* __restrict__ Hs,
                                             unsigned short* __restrict__ HnT,
                                             float* __restrict__ es_out,
                                             float* __restrict__ en_out,
                                             unsigned* __restrict__ P) {
  __shared__ float4 lin4[8 * 64];  // 8 KB (proj role only)
  const int bid = blockIdx.x;
  const int q5 = bid / 5, r5 = bid - q5 * 5;
  const int t = threadIdx.x;

  if (r5 == 4) {
    // ---- pack role: rows q5*32 .. q5*32+31 -> P[row][j/32] ----
    const int row0 = q5 * 32;
#pragma unroll 1
    for (int k = 0; k < 32; ++k) {
      int g = t + k * 256;            // 0..8191
      int rr = g >> 8;                // 0..31
      int c8 = g & 255;               // word-in-row
      const int4* src = (const int4*)(A + (size_t)(row0 + rr) * NN + c8 * 32);
      int4 v0 = src[0], v1 = src[1], v2 = src[2], v3 = src[3];
      int4 v4 = src[4], v5 = src[5], v6 = src[6], v7 = src[7];
      unsigned w = pack4(v0, 0)  | pack4(v1, 4)  | pack4(v2, 8)  | pack4(v3, 12) |
                   pack4(v4, 16) | pack4(v5, 20) | pack4(v6, 24) | pack4(v7, 28);
      P[(size_t)(row0 + rr) * 256 + c8] = w;
    }
    return;
  }

  // ---- proj role (verified body): 8 rows, i0 = (q5*4+r5)*8 ----
  const int i0 = (q5 * 4 + r5) * 8;
  const float4* Xg = (const float4*)X + (size_t)i0 * 64;
  lin4[t] = Xg[t];
  lin4[t + 256] = Xg[t + 256];
  __syncthreads();
  const int c = t & 127;
  const int rh = t >> 7;  // 0..1, 4 rows each
  float accs[4], accn[4];
#pragma unroll
  for (int r = 0; r < 4; ++r) { accs[r] = 0.f; accn[r] = 0.f; }
  for (int k = 0; k < 256; k += 4) {
    float ws0 = Ws[(k + 0) * 128 + c], ws1 = Ws[(k + 1) * 128 + c];
    float ws2 = Ws[(k + 2) * 128 + c], ws3 = Ws[(k + 3) * 128 + c];
    float wn0 = Wn[(k + 0) * 128 + c], wn1 = Wn[(k + 1) * 128 + c];
    float wn2 = Wn[(k + 2) * 128 + c], wn3 = Wn[(k + 3) * 128 + c];
#pragma unroll
    for (int r = 0; r < 4; ++r) {
      float4 iv = lin4[(rh * 4 + r) * 64 + (k >> 2)];  // wave-uniform broadcast
      accs[r] = fmaf(iv.x, ws0, accs[r]); accs[r] = fmaf(iv.y, ws1, accs[r]);
      accs[r] = fmaf(iv.z, ws2, accs[r]); accs[r] = fmaf(iv.w, ws3, accs[r]);
      accn[r] = fmaf(iv.x, wn0, accn[r]); accn[r] = fmaf(iv.y, wn1, accn[r]);
      accn[r] = fmaf(iv.z, wn2, accn[r]); accn[r] = fmaf(iv.w, wn3, accn[r]);
    }
  }
  // Hs fp32 out
#pragma unroll
  for (int r = 0; r < 4; ++r)
    Hs[(size_t)(i0 + rh * 4 + r) * 128 + c] = accs[r];
  // HnT bf16 out, j-block-major: elem(jb=j/8, f, ji=j%8) at jb*1024 + f*8 + ji.
  {
    union { unsigned short us[4]; ushort4 u4; } pk;
#pragma unroll
    for (int r = 0; r < 4; ++r) pk.us[r] = f2bf(accn[r]);
    *(ushort4*)(HnT + (size_t)(i0 >> 3) * 1024 + c * 8 + rh * 4) = pk.u4;
  }
  // ---- fused reductions -> es = exp(s), en = exp(n) ----
  float* red = (float*)lin4;  // 8 x 128 f32 = 4 KB
  const int wv = t >> 6, ln = t & 63;
  __syncthreads();
  {
    float av = as_[c];
#pragma unroll
    for (int r = 0; r < 4; ++r) red[(rh * 4 + r) * 128 + c] = accs[r] * av;
  }
  __syncthreads();
#pragma unroll
  for (int h = 0; h < 2; ++h) {
    int row = wv * 2 + h;
    float p = red[row * 128 + ln] + red[row * 128 + 64 + ln];
#pragma unroll
    for (int off = 32; off >= 1; off >>= 1) p += __shfl_down(p, off);
    if (ln == 0) es_out[i0 + row] = __expf(p);
  }
  __syncthreads();
  {
    float av = an_[c];
#pragma unroll
    for (int r = 0; r < 4; ++r) red[(rh * 4 + r) * 128 + c] = accn[r] * av;
  }
  __syncthreads();
#pragma unroll
  for (int h = 0; h < 2; ++h) {
    int row = wv * 2 + h;
    float p = red[row * 128 + ln] + red[row * 128 + 64 + ln];
#pragma unroll
    for (int off = 32; off >= 1; off >>= 1) p += __shfl_down(p, off);
    if (ln == 0) en_out[i0 + row] = __expf(p);
  }
}

// ---------------- Kernel 2: attention GEMM + softmax + elu ----------------
// Verified at 418.3 (R6 source), ONE delta: s_setprio removed (m190: setprio
// is neutral-to-harmful on barrier-free GEMM structures; MfmaUtil here is 4%
// so MFMA-wave priority only delays other waves' load issue). Block 512
// (8 waves), 16 rows/block, grid 512. Prologue stages en (32 KB) + bits
// (16 KB, from global P) into LDS; steady-state loop has ONE VMEM class
// (breg = HnT f-tiles, L2-resident), zero branches, single-generation breg
// issued after the MFMA block. w = bit ? max(es*en, 1) : 0. Epilogue:
// two-stage cross-wave combine, LDS 48 KB total.
__global__ __launch_bounds__(512, 4) void k_main(const unsigned* __restrict__ Pk,
                                                 const unsigned short* __restrict__ HnT,
                                                 const float* __restrict__ es_g,
                                                 const float* __restrict__ en_g,
                                                 float* __restrict__ HsOut) {
  __shared__ __align__(16) char smem[49152];           // 48 KB
  float* en_lds = (float*)smem;                        // 8192 f32 = 32 KB (loop)
  unsigned* bits_lds = (unsigned*)(smem + 32768);      // 4096 u32 = 16 KB (loop)
  float* cmb = (float*)smem;                           // 4*16*128 f32 = 32 KB (epilogue)
  __shared__ float zsh[8][16];
  __shared__ float zf[16];

  const int t = threadIdx.x;
  const int wv = t >> 6;   // wave 0..7 = j-partition
  const int ln = t & 63;
  const int q = ln >> 4;   // quad -> k-slice within K=32
  const int m = ln & 15;   // A row / B col / C col
  const int row0 = blockIdx.x * 16;

  // ---- prologue: stage en (8192 f32) and this block's bits (16x256 u32) ----
  {
    float4* dst = (float4*)en_lds;
    const float4* s4 = (const float4*)en_g;
#pragma unroll
    for (int k = 0; k < 4; ++k) dst[t + k * 512] = s4[t + k * 512];
#pragma unroll
    for (int k = 0; k < 8; ++k) {
      int g = t + k * 512;            // 0..4095
      int rr = g >> 8;                // row-in-block 0..15
      int c8 = g & 255;               // word-in-row
      unsigned w = Pk[(size_t)(row0 + rr) * 256 + c8];
      // LDS layout [wv][tt][m]: conflict-free broadcast read per step
      bits_lds[(c8 >> 5) * 512 + (c8 & 31) * 16 + rr] = w;
    }
  }

  const float sme = es_g[row0 + m];
  // HnT elem(jb, f, ji) at jb*1024 + f*8 + ji ; lane base: jb = wv*128 + q, f = m
  const unsigned short* bptr = HnT + ((size_t)(wv * 128 + q) * 128 + m) * 8;
  const float* nvl = en_lds + wv * 1024 + q * 8;       // + tt*32
  const unsigned* bts = bits_lds + wv * 512 + m;       // + tt*16

  f32x4 acc[8];
#pragma unroll
  for (int ft = 0; ft < 8; ++ft) acc[ft] = (f32x4){0.f, 0.f, 0.f, 0.f};
  float zp = 0.f;

  union Breg { uint4 u; short8 s; };
  Breg breg[8];

  __syncthreads();  // LDS stage complete

  // breg(0)
  breg[0].u = *(const uint4*)(bptr);       breg[1].u = *(const uint4*)(bptr + 128);
  breg[2].u = *(const uint4*)(bptr + 256); breg[3].u = *(const uint4*)(bptr + 384);
  breg[4].u = *(const uint4*)(bptr + 512); breg[5].u = *(const uint4*)(bptr + 640);
  breg[6].u = *(const uint4*)(bptr + 768); breg[7].u = *(const uint4*)(bptr + 896);

#pragma unroll 2
  for (int tt = 0; tt < 32; ++tt) {
    // ---- A-frag from LDS: w for rows m, j = wv*1024 + tt*32 + q*8 .. +7 ----
    short8 fr;
    {
      float4 nv0 = *(const float4*)(nvl + tt * 32);
      float4 nv1 = *(const float4*)(nvl + tt * 32 + 4);
      const unsigned bw = bts[tt * 16];
      const unsigned byte = (bw >> (q * 8)) & 0xffu;
      float ev[8] = {nv0.x, nv0.y, nv0.z, nv0.w, nv1.x, nv1.y, nv1.z, nv1.w};
#pragma unroll
      for (int k = 0; k < 8; ++k) {
        float w = ((byte >> k) & 1u) ? fmaxf(sme * ev[k], 1.f) : 0.f;
        zp += w;
        fr[k] = (short)f2bf(w);
      }
    }
    // ---- MFMA: consumes breg(tt) issued last iteration ----
    acc[0] = __builtin_amdgcn_mfma_f32_16x16x32_bf16(fr, breg[0].s, acc[0], 0, 0, 0);
    acc[1] = __builtin_amdgcn_mfma_f32_16x16x32_bf16(fr, breg[1].s, acc[1], 0, 0, 0);
    acc[2] = __builtin_amdgcn_mfma_f32_16x16x32_bf16(fr, breg[2].s, acc[2], 0, 0, 0);
    acc[3] = __builtin_amdgcn_mfma_f32_16x16x32_bf16(fr, breg[3].s, acc[3], 0, 0, 0);
    acc[4] = __builtin_amdgcn_mfma_f32_16x16x32_bf16(fr, breg[4].s, acc[4], 0, 0, 0);
    acc[5] = __builtin_amdgcn_mfma_f32_16x16x32_bf16(fr, breg[5].s, acc[5], 0, 0, 0);
    acc[6] = __builtin_amdgcn_mfma_f32_16x16x32_bf16(fr, breg[6].s, acc[6], 0, 0, 0);
    acc[7] = __builtin_amdgcn_mfma_f32_16x16x32_bf16(fr, breg[7].s, acc[7], 0, 0, 0);
    // ---- issue breg(tt+1), branch-free; tt=31 overruns <=8 KB into the
    // adjacent es/en workspace region (read-only, discarded) ----
    {
      const unsigned short* p = bptr + (size_t)(tt + 1) * 4096;  // +4 j-blocks
      breg[0].u = *(const uint4*)(p);       breg[1].u = *(const uint4*)(p + 128);
      breg[2].u = *(const uint4*)(p + 256); breg[3].u = *(const uint4*)(p + 384);
      breg[4].u = *(const uint4*)(p + 512); breg[5].u = *(const uint4*)(p + 640);
      breg[6].u = *(const uint4*)(p + 768); breg[7].u = *(const uint4*)(p + 896);
    }
  }

  // ---- per-wave Z partial for each row m: reduce over q ----
  {
    float zz = zp;
    zz += __shfl_down(zz, 32);
    zz += __shfl_down(zz, 16);
    if (ln < 16) zsh[wv][ln] = zz;
  }
  __syncthreads();  // all waves done reading en/bits LDS; zsh ready
  // ---- stage 1: waves 4..7 dump partials (32 KB, aliases en/bits) ----
  if (wv >= 4) {
#pragma unroll
    for (int ft = 0; ft < 8; ++ft)
#pragma unroll
      for (int reg = 0; reg < 4; ++reg)
        cmb[(wv - 4) * 2048 + (q * 4 + reg) * 128 + ft * 16 + m] = acc[ft][reg];
  }
  __syncthreads();
  // ---- stage 2: waves 0..3 accumulate partner wave's partials ----
  if (wv < 4) {
#pragma unroll
    for (int ft = 0; ft < 8; ++ft)
#pragma unroll
      for (int reg = 0; reg < 4; ++reg)
        acc[ft][reg] += cmb[wv * 2048 + (q * 4 + reg) * 128 + ft * 16 + m];
  }
  __syncthreads();
  // ---- stage 3: waves 0..3 dump combined partials ----
  if (wv < 4) {
#pragma unroll
    for (int ft = 0; ft < 8; ++ft)
#pragma unroll
      for (int reg = 0; reg < 4; ++reg)
        cmb[wv * 2048 + (q * 4 + reg) * 128 + ft * 16 + m] = acc[ft][reg];
  }
  if (t < 16) {
    float z = zsh[0][t] + zsh[1][t] + zsh[2][t] + zsh[3][t] +
              zsh[4][t] + zsh[5][t] + zsh[6][t] + zsh[7][t];
    zf[t] = 1.f / z;
  }
  __syncthreads();
  // ---- final: 4-way sum + epilogue out = elu(0.5*h_s + acc/Z) ----
  {
    const int row = t >> 5;        // 0..15
    const int f0 = (t & 31) * 4;   // 0..124
    f32x4 ssum = *(const f32x4*)&cmb[row * 128 + f0];
#pragma unroll
    for (int w = 1; w < 4; ++w) ssum += *(const f32x4*)&cmb[w * 2048 + row * 128 + f0];
    const float invz = zf[row];
    const size_t off = (size_t)(row0 + row) * 128 + f0;
    float4 h = *(const float4*)(HsOut + off);
    float4 o;
    o.x = eluf(fmaf(ssum[0], invz, 0.5f * h.x));
    o.y = eluf(fmaf(ssum[1], invz, 0.5f * h.y));
    o.z = eluf(fmaf(ssum[2], invz, 0.5f * h.z));
    o.w = eluf(fmaf(ssum[3], invz, 0.5f * h.w));
    *(float4*)(HsOut + off) = o;
  }
}

extern "C" void kernel_launch(void* const* d_in, const int* in_sizes, int n_in,
                              void* d_out, int out_size, void* d_ws, size_t ws_size,
                              hipStream_t stream) {
  const float* X   = (const float*)d_in[0];
  const int*   A   = (const int*)d_in[1];
  const float* Ws  = (const float*)d_in[2];
  const float* as_ = (const float*)d_in[3];
  const float* Wn  = (const float*)d_in[4];
  const float* an_ = (const float*)d_in[5];
  float* out = (float*)d_out;  // holds h_s, then final output (in-place epilogue)

  unsigned short* HnT = (unsigned short*)d_ws;       // 2 MB (j-block-major)
  float* es = (float*)(HnT + (size_t)128 * NN);      // 8192 f32 = exp(s)
  float* en = es + NN;                               // 8192 f32 = exp(n)
  unsigned* P = (unsigned*)(en + NN);                // 8 MB bitmask (ws is 1 GiB)

  k_pre<<<1280, 256, 0, stream>>>(X, A, Ws, Wn, as_, an_, out, HnT, es, en, P);
  k_main<<<512, 512, 0, stream>>>(P, HnT, es, en, out);
}